// Round 3
// baseline (181.565 us; speedup 1.0000x reference)
//
#include <hip/hip_runtime.h>

#define NN   21   // nodes
#define NE   60   // edges (before self-loops)
#define FD   3    // input features
#define HD   32   // hidden
#define PP   64   // periods
#define OUTC 6    // output channels

// ws float offsets
#define WS_A    0      // 441  dense normalized adjacency A[dst][src]
#define WS_PROB 441    // 64   softmax(att)
#define WS_WZ   505    // 96   fused W'_z = W_z @ lz_W[:32]
#define WS_BZ   601    // 32   fused b'_z = b_z @ lz_W[:32] + lz_b
#define WS_WH   633    // 96   fused W'_h
#define WS_BH   729    // 32   fused b'_h

// ---------------------------------------------------------------------------
// Kernel 1: build dense adjacency, softmax(att), fused gate weights.
// One tiny block; runs once per launch.
// ---------------------------------------------------------------------------
__global__ void setup_k(const int* __restrict__ edge,
                        const float* __restrict__ Wz, const float* __restrict__ bz,
                        const float* __restrict__ Wh, const float* __restrict__ bh,
                        const float* __restrict__ lzW, const float* __restrict__ lzb,
                        const float* __restrict__ lhW, const float* __restrict__ lhb,
                        const float* __restrict__ att,
                        float* __restrict__ ws) {
    __shared__ float sA[NN * NN];
    const int t = threadIdx.x;

    for (int i = t; i < NN * NN; i += blockDim.x) sA[i] = 0.f;
    __syncthreads();

    if (t == 0) {
        // degrees with self-loops
        float dinv[NN];
        {
            float deg[NN];
            for (int n = 0; n < NN; ++n) deg[n] = 1.f;           // self loop
            for (int e = 0; e < NE; ++e) deg[edge[NE + e]] += 1.f;
            for (int n = 0; n < NN; ++n) dinv[n] = rsqrtf(deg[n]);
        }
        // A[d][s] += dinv[s]*dinv[d]  (duplicates accumulate, like scatter-add)
        for (int e = 0; e < NE; ++e) {
            int s = edge[e], d = edge[NE + e];
            sA[d * NN + s] += dinv[s] * dinv[d];
        }
        for (int n = 0; n < NN; ++n) sA[n * NN + n] += dinv[n] * dinv[n];

        // probs = softmax(att)
        float m = att[0];
        for (int p = 1; p < PP; ++p) m = fmaxf(m, att[p]);
        float ssum = 0.f;
        for (int p = 0; p < PP; ++p) ssum += expf(att[p] - m);
        float inv = 1.f / ssum;
        for (int p = 0; p < PP; ++p) ws[WS_PROB + p] = expf(att[p] - m) * inv;
    }
    __syncthreads();

    for (int i = t; i < NN * NN; i += blockDim.x) ws[WS_A + i] = sA[i];

    // fused gate weights: W' = W @ lW_top  (top half of lW; H=0 kills bottom)
    if (t < FD * HD) {
        int f = t >> 5, o = t & (HD - 1);
        float az = 0.f, ah = 0.f;
        for (int k = 0; k < HD; ++k) {
            az += Wz[f * HD + k] * lzW[k * HD + o];
            ah += Wh[f * HD + k] * lhW[k * HD + o];
        }
        ws[WS_WZ + t] = az;
        ws[WS_WH + t] = ah;
    } else if (t < FD * HD + HD) {
        int o = t - FD * HD;
        float az = lzb[o], ah = lhb[o];
        for (int k = 0; k < HD; ++k) {
            az += bz[k] * lzW[k * HD + o];
            ah += bh[k] * lhW[k * HD + o];
        }
        ws[WS_BZ + o] = az;
        ws[WS_BH + o] = ah;
    }
}

// ---------------------------------------------------------------------------
// Kernel 2: one block per batch element.
//   Xs[b] -> Ys = A @ X (all periods) -> per-(n,o) GRU-collapsed gate math with
//   attention pooling over p in registers -> relu -> l1 -> transpose -> l2.
// ---------------------------------------------------------------------------
__global__ __launch_bounds__(256) void main_k(const float* __restrict__ x,
                                              const float* __restrict__ ws,
                                              const float* __restrict__ l1W,
                                              const float* __restrict__ l1b,
                                              const float* __restrict__ l2W,
                                              const float* __restrict__ l2b,
                                              float* __restrict__ out) {
    __shared__ float Xs[NN * FD * PP];   // 16128 B; reused as T1[PP][NN] later
    __shared__ float Ys[NN * FD * PP];   // 16128 B
    __shared__ float As[NN * NN];
    __shared__ float probs[PP];
    __shared__ float Wzp[FD * HD], Whp[FD * HD], bzp[HD], bhp[HD];
    __shared__ float Hs[NN * HD];
    __shared__ float l1Ws[HD * PP];
    __shared__ float l1bs[PP];
    __shared__ float l2Ws[NN * OUTC];
    __shared__ float l2bs[OUTC];

    const int t = threadIdx.x;
    const int b = blockIdx.x;
    const float* xb = x + (size_t)b * (NN * FD * PP);

    // ---- stage 0: load everything into LDS (x[b] is contiguous -> coalesced)
    for (int i = t; i < NN * FD * PP; i += 256) Xs[i] = xb[i];
    for (int i = t; i < NN * NN; i += 256)      As[i] = ws[WS_A + i];
    if (t < PP)                                 probs[t] = ws[WS_PROB + t];
    if (t < FD * HD) { Wzp[t] = ws[WS_WZ + t];  Whp[t] = ws[WS_WH + t]; }
    if (t >= 128 && t < 128 + HD) {
        bzp[t - 128] = ws[WS_BZ + t - 128];
        bhp[t - 128] = ws[WS_BH + t - 128];
    }
    for (int i = t; i < HD * PP; i += 256)      l1Ws[i] = l1W[i];
    if (t < PP)                                 l1bs[t] = l1b[t];
    if (t < NN * OUTC)                          l2Ws[t] = l2W[t];
    if (t < OUTC)                               l2bs[t] = l2b[t];
    __syncthreads();

    // ---- stage 1: Ys[n][f][p] = sum_m A[n][m] * Xs[m][f][p]
    for (int i = t; i < NN * FD * PP; i += 256) {
        int p  = i & (PP - 1);
        int fn = i >> 6;          // = n*3 + f
        int f  = fn % FD;
        int n  = fn / FD;
        float acc = 0.f;
        for (int m = 0; m < NN; ++m)
            acc = fmaf(As[n * NN + m], Xs[(m * FD + f) * PP + p], acc);
        Ys[i] = acc;
    }
    __syncthreads();

    // ---- stage 2: Hs[n][o] = relu( sum_p probs[p] * (1-Z) * Ht )
    {
        const int o  = t & (HD - 1);
        const int ng = t >> 5;    // 0..7
        const float wz0 = Wzp[0 * HD + o], wz1 = Wzp[1 * HD + o], wz2 = Wzp[2 * HD + o];
        const float wh0 = Whp[0 * HD + o], wh1 = Whp[1 * HD + o], wh2 = Whp[2 * HD + o];
        const float bz0 = bzp[o], bh0 = bhp[o];
        for (int n = ng; n < NN; n += 8) {
            const float* Yn = &Ys[n * FD * PP];
            float acc = 0.f;
            for (int p = 0; p < PP; ++p) {
                float y0 = Yn[p], y1 = Yn[PP + p], y2 = Yn[2 * PP + p];
                float az = fmaf(y2, wz2, fmaf(y1, wz1, fmaf(y0, wz0, bz0)));
                float ah = fmaf(y2, wh2, fmaf(y1, wh1, fmaf(y0, wh0, bh0)));
                float z  = 1.f / (1.f + __expf(-az));              // sigmoid
                float e2 = __expf(2.f * ah);
                float ht = 1.f - 2.f / (e2 + 1.f);                 // tanh
                acc = fmaf(probs[p] * (1.f - z), ht, acc);
            }
            Hs[n * HD + o] = fmaxf(acc, 0.f);                      // relu fused
        }
    }
    __syncthreads();

    // ---- stage 3: l1 + transpose into T1[q][n] (T1 overlays Xs, now dead)
    float* T1 = Xs;
    for (int i = t; i < NN * PP; i += 256) {
        int q = i & (PP - 1);
        int n = i >> 6;
        float acc = l1bs[q];
        for (int o = 0; o < HD; ++o)
            acc = fmaf(Hs[n * HD + o], l1Ws[o * PP + q], acc);
        T1[q * NN + n] = acc;
    }
    __syncthreads();

    // ---- stage 4: l2 + final transpose; out[b][c][q]
    // OUTC*PP = 384 > 256 threads -> MUST be a strided loop (round-1 bug:
    // `if (t < 384)` truncated at t<256 so channels c=4,5 were never written)
    for (int i = t; i < OUTC * PP; i += 256) {
        int c = i >> 6;
        int q = i & (PP - 1);
        float acc = l2bs[c];
        for (int n = 0; n < NN; ++n)
            acc = fmaf(T1[q * NN + n], l2Ws[n * OUTC + c], acc);
        out[(size_t)b * (OUTC * PP) + c * PP + q] = acc;
    }
}

extern "C" void kernel_launch(void* const* d_in, const int* in_sizes, int n_in,
                              void* d_out, int out_size, void* d_ws, size_t ws_size,
                              hipStream_t stream) {
    const float* x   = (const float*)d_in[0];
    const int*   ei  = (const int*)  d_in[1];
    const float* Wz  = (const float*)d_in[2];
    const float* bz  = (const float*)d_in[3];
    // d_in[4], d_in[5] (W_r, b_r) are dead: H=0 -> reset gate never used
    const float* Wh  = (const float*)d_in[6];
    const float* bh  = (const float*)d_in[7];
    const float* lzW = (const float*)d_in[8];
    const float* lzb = (const float*)d_in[9];
    // d_in[10], d_in[11] (lr_W, lr_b) dead for the same reason
    const float* lhW = (const float*)d_in[12];
    const float* lhb = (const float*)d_in[13];
    const float* att = (const float*)d_in[14];
    const float* l1W = (const float*)d_in[15];
    const float* l1b = (const float*)d_in[16];
    const float* l2W = (const float*)d_in[17];
    const float* l2b = (const float*)d_in[18];

    float* out = (float*)d_out;
    float* ws  = (float*)d_ws;

    const int B = in_sizes[0] / (NN * FD * PP);   // 1024

    setup_k<<<1, 128, 0, stream>>>(ei, Wz, bz, Wh, bh, lzW, lzb, lhW, lhb, att, ws);
    main_k<<<B, 256, 0, stream>>>(x, ws, l1W, l1b, l2W, l2b, out);
}

// Round 4
// 154.443 us; speedup vs baseline: 1.1756x; 1.1756x over previous
//
#include <hip/hip_runtime.h>

#define NN   21   // nodes
#define NE   60   // edges (before self-loops)
#define FD   3    // input features
#define HD   32   // hidden
#define PP   64   // periods
#define OUTC 6    // output channels

// Single fused kernel: one block per batch element. Each block redoes the tiny
// shared setup (adjacency, softmax(att), weight fusion) in ~2us of fully
// parallel LDS work -- removes the old serial 1-block setup kernel (scratch-
// indexed arrays, whole-GPU idle) and the inter-kernel dependency gap.
//
// Algebra used:
//   H=0  =>  R dead, Z = sigma(Y@W'z + b'z), Ht = tanh(Y@W'h + b'h),
//            Hn = (1-Z)*Ht, where Y = A@X and W' = W @ lW_top (fused).
//   No nonlinearity between l1 and l2:
//     out[b,c,p] = sum_o G[c,o]*l1W[o,p] + Sc[c]*l1b[p] + l2b[c]
//     G[c,o]     = sum_n l2W[n,c]*Hs[n,o],  Sc[c] = sum_n l2W[n,c]
__global__ __launch_bounds__(256, 4) void fused_k(
    const float* __restrict__ x,   const int* __restrict__ edge,
    const float* __restrict__ Wz,  const float* __restrict__ bz,
    const float* __restrict__ Wh,  const float* __restrict__ bh,
    const float* __restrict__ lzW, const float* __restrict__ lzb,
    const float* __restrict__ lhW, const float* __restrict__ lhb,
    const float* __restrict__ att,
    const float* __restrict__ l1W, const float* __restrict__ l1b,
    const float* __restrict__ l2W, const float* __restrict__ l2b,
    float* __restrict__ out)
{
    // LDS budget: 16128+16128+1764+84+256+384+384+128+128+2688+768+24
    //           = 38864 B  -> 4 blocks/CU (4*38864 < 160 KiB)
    __shared__ __align__(16) float Xs[NN * FD * PP]; // x[b]; after stage1: l1W/l1b/l2W/l2b overlay
    __shared__ __align__(16) float Ys[NN * FD * PP]; // P0-P3: weight scratch; then Y = A@X
    __shared__ float As[NN * NN];
    __shared__ float degS[NN];
    __shared__ float probs[PP];
    __shared__ float Wzp[FD * HD], Whp[FD * HD], bzp[HD], bhp[HD];
    __shared__ float Hs[NN * HD];
    __shared__ float G[OUTC * HD];
    __shared__ float Sc[OUTC];

    const int t = threadIdx.x;
    const int b = blockIdx.x;
    const float* xb = x + (size_t)b * (NN * FD * PP);

    // ---- P0: stage x -> Xs (float4), lzW/lhW top halves + Wz/Wh -> Ys scratch,
    //          zero As, init deg (self-loop = 1)
    {
        const float4* xb4 = (const float4*)xb;
        float4* Xs4 = (float4*)Xs;
        for (int i = t; i < NN * FD * PP / 4; i += 256) Xs4[i] = xb4[i];

        float4* Ys4 = (float4*)Ys;
        // lzW rows 0..31 (top half, [64][32] row-major => first 1024 floats)
        Ys4[t]       = ((const float4*)lzW)[t];   // Ys[0..1023]
        Ys4[256 + t] = ((const float4*)lhW)[t];   // Ys[1024..2047]
        if (t < 24)                 Ys4[512 + t]        = ((const float4*)Wz)[t];      // Ys[2048..2143]
        else if (t >= 32 && t < 56) Ys4[536 + (t - 32)] = ((const float4*)Wh)[t - 32]; // Ys[2144..2239]

        for (int i = t; i < NN * NN; i += 256) As[i] = 0.f;
        if (t < NN) degS[t] = 1.f;
    }
    __syncthreads();

    // ---- P1: degree scatter (LDS atomics; duplicates accumulate like .at[].add)
    if (t < NE) atomicAdd(&degS[edge[NE + t]], 1.f);
    __syncthreads();

    // ---- P2: deg -> deg^-1/2 in place (each thread its own slot)
    if (t < NN) degS[t] = rsqrtf(degS[t]);
    __syncthreads();

    // ---- P3: adjacency atomics + fused gate weights + softmax(att), in parallel
    if (t < NE) {
        int s = edge[t], d = edge[NE + t];
        atomicAdd(&As[d * NN + s], degS[s] * degS[d]);
    }
    if (t >= 192 && t < 192 + NN) {           // self-loop diagonal
        int n = t - 192;
        atomicAdd(&As[n * NN + n], degS[n] * degS[n]);
    }
    if (t < FD * HD) {                        // W' = W @ lW_top
        int f = t >> 5, o = t & 31;
        const float* lzWs = Ys;
        const float* lhWs = Ys + 1024;
        const float* WzS  = Ys + 2048;
        const float* WhS  = Ys + 2144;
        float az = 0.f, ah = 0.f;
        #pragma unroll
        for (int k = 0; k < HD; ++k) {
            az = fmaf(WzS[f * HD + k], lzWs[k * HD + o], az);
            ah = fmaf(WhS[f * HD + k], lhWs[k * HD + o], ah);
        }
        Wzp[t] = az; Whp[t] = ah;
    } else if (t < FD * HD + HD) {            // b' = b @ lW_top + lb
        int o = t - FD * HD;
        const float* lzWs = Ys;
        const float* lhWs = Ys + 1024;
        float az = lzb[o], ah = lhb[o];
        #pragma unroll
        for (int k = 0; k < HD; ++k) {
            az = fmaf(bz[k], lzWs[k * HD + o], az);
            ah = fmaf(bh[k], lhWs[k * HD + o], ah);
        }
        bzp[o] = az; bhp[o] = ah;
    } else if (t >= 128 && t < 192) {         // softmax(att), one full wave
        int l = t - 128;
        float a = att[l];
        float m = a;
        #pragma unroll
        for (int msk = 32; msk >= 1; msk >>= 1) m = fmaxf(m, __shfl_xor(m, msk, 64));
        float e = __expf(a - m);
        float ssum = e;
        #pragma unroll
        for (int msk = 32; msk >= 1; msk >>= 1) ssum += __shfl_xor(ssum, msk, 64);
        probs[l] = e / ssum;
    }
    __syncthreads();

    // ---- Stage 1: Ys[n][f][p] = sum_m A[n][m] * Xs[m][f][p]  (float4 over p)
    {
        float4* Ys4 = (float4*)Ys;
        const float4* Xs4 = (const float4*)Xs;
        for (int i = t; i < NN * FD * PP / 4; i += 256) {
            int p4 = i & 15;
            int fn = i >> 4;            // n*3 + f
            int f = fn % 3, n = fn / 3;
            const float* Arow = As + n * NN;
            float4 acc = {0.f, 0.f, 0.f, 0.f};
            #pragma unroll
            for (int m = 0; m < NN; ++m) {
                float a = Arow[m];
                float4 xv = Xs4[(m * 3 + f) * 16 + p4];
                acc.x = fmaf(a, xv.x, acc.x);
                acc.y = fmaf(a, xv.y, acc.y);
                acc.z = fmaf(a, xv.z, acc.z);
                acc.w = fmaf(a, xv.w, acc.w);
            }
            Ys4[fn * 16 + p4] = acc;
        }
    }
    __syncthreads();

    // ---- overlay loads into now-dead Xs region (latency hides under stage 2;
    //      stage-2-end barrier publishes them for stages 3'/4')
    {
        float4* ov4 = (float4*)Xs;
        const float4* l1W4 = (const float4*)l1W;
        for (int i = t; i < 512; i += 256) ov4[i] = l1W4[i];        // Xs[0..2047]    l1W [32][64]
        if (t < 16) ov4[512 + t] = ((const float4*)l1b)[t];         // Xs[2048..2111] l1b
        if (t >= 64 && t < 64 + 126) Xs[2112 + (t - 64)] = l2W[t - 64]; // Xs[2112..2237] l2W [21][6]
        if (t >= 224 && t < 230) Xs[2238 + (t - 224)] = l2b[t - 224];   // Xs[2238..2243] l2b
    }

    // ---- Stage 2: Hs[n][o] = relu( sum_p probs[p]*(1-Z)*Ht ), 4-way p-unroll
    {
        const int o  = t & 31;
        const int ng = t >> 5;          // 0..7
        const float wz0 = Wzp[o], wz1 = Wzp[HD + o], wz2 = Wzp[2 * HD + o];
        const float wh0 = Whp[o], wh1 = Whp[HD + o], wh2 = Whp[2 * HD + o];
        const float bz0 = bzp[o], bh0 = bhp[o];
        for (int n = ng; n < NN; n += 8) {
            const float4* Yn4 = (const float4*)(Ys + n * FD * PP);
            float a0 = 0.f, a1 = 0.f, a2 = 0.f, a3 = 0.f;
            #pragma unroll
            for (int pq = 0; pq < 16; ++pq) {
                float4 y0 = Yn4[pq], y1 = Yn4[16 + pq], y2 = Yn4[32 + pq];
                {   // p = 4*pq+0
                    float az = fmaf(y2.x, wz2, fmaf(y1.x, wz1, fmaf(y0.x, wz0, bz0)));
                    float ah = fmaf(y2.x, wh2, fmaf(y1.x, wh1, fmaf(y0.x, wh0, bh0)));
                    float w  = __builtin_amdgcn_rcpf(1.f + __expf(az));        // = 1-Z
                    float r  = __builtin_amdgcn_rcpf(1.f + __expf(2.f * ah));
                    float ht = fmaf(-2.f, r, 1.f);                             // tanh
                    a0 = fmaf(probs[4 * pq + 0] * w, ht, a0);
                }
                {   // p = 4*pq+1
                    float az = fmaf(y2.y, wz2, fmaf(y1.y, wz1, fmaf(y0.y, wz0, bz0)));
                    float ah = fmaf(y2.y, wh2, fmaf(y1.y, wh1, fmaf(y0.y, wh0, bh0)));
                    float w  = __builtin_amdgcn_rcpf(1.f + __expf(az));
                    float r  = __builtin_amdgcn_rcpf(1.f + __expf(2.f * ah));
                    float ht = fmaf(-2.f, r, 1.f);
                    a1 = fmaf(probs[4 * pq + 1] * w, ht, a1);
                }
                {   // p = 4*pq+2
                    float az = fmaf(y2.z, wz2, fmaf(y1.z, wz1, fmaf(y0.z, wz0, bz0)));
                    float ah = fmaf(y2.z, wh2, fmaf(y1.z, wh1, fmaf(y0.z, wh0, bh0)));
                    float w  = __builtin_amdgcn_rcpf(1.f + __expf(az));
                    float r  = __builtin_amdgcn_rcpf(1.f + __expf(2.f * ah));
                    float ht = fmaf(-2.f, r, 1.f);
                    a2 = fmaf(probs[4 * pq + 2] * w, ht, a2);
                }
                {   // p = 4*pq+3
                    float az = fmaf(y2.w, wz2, fmaf(y1.w, wz1, fmaf(y0.w, wz0, bz0)));
                    float ah = fmaf(y2.w, wh2, fmaf(y1.w, wh1, fmaf(y0.w, wh0, bh0)));
                    float w  = __builtin_amdgcn_rcpf(1.f + __expf(az));
                    float r  = __builtin_amdgcn_rcpf(1.f + __expf(2.f * ah));
                    float ht = fmaf(-2.f, r, 1.f);
                    a3 = fmaf(probs[4 * pq + 3] * w, ht, a3);
                }
            }
            Hs[n * HD + o] = fmaxf((a0 + a1) + (a2 + a3), 0.f);
        }
    }
    __syncthreads();

    // ---- Stage 3': G[c,o] = sum_n l2W[n,c]*Hs[n,o];  Sc[c] = sum_n l2W[n,c]
    {
        const float* l2Ws = Xs + 2112;
        if (t < OUTC * HD) {
            int c = t >> 5, o = t & 31;
            float g = 0.f;
            #pragma unroll
            for (int n = 0; n < NN; ++n) g = fmaf(l2Ws[n * OUTC + c], Hs[n * HD + o], g);
            G[t] = g;
        } else if (t < OUTC * HD + OUTC) {
            int c = t - OUTC * HD;
            float s = 0.f;
            #pragma unroll
            for (int n = 0; n < NN; ++n) s += l2Ws[n * OUTC + c];
            Sc[c] = s;
        }
    }
    __syncthreads();

    // ---- Stage 4': out[b,c,p] = sum_o G[c,o]*l1W[o,p] + Sc[c]*l1b[p] + l2b[c]
    {
        const float* l1Ws = Xs;              // [32][64]
        const float* l1bs = Xs + 2048;
        const float* l2bs = Xs + 2238;
        for (int i = t; i < OUTC * PP; i += 256) {
            int c = i >> 6, p = i & 63;
            float acc = fmaf(Sc[c], l1bs[p], l2bs[c]);
            #pragma unroll
            for (int o = 0; o < HD; ++o)
                acc = fmaf(G[c * HD + o], l1Ws[o * PP + p], acc);
            out[(size_t)b * (OUTC * PP) + i] = acc;
        }
    }
}

extern "C" void kernel_launch(void* const* d_in, const int* in_sizes, int n_in,
                              void* d_out, int out_size, void* d_ws, size_t ws_size,
                              hipStream_t stream) {
    const float* x   = (const float*)d_in[0];
    const int*   ei  = (const int*)  d_in[1];
    const float* Wz  = (const float*)d_in[2];
    const float* bz  = (const float*)d_in[3];
    // d_in[4], d_in[5] (W_r, b_r) dead: H=0 -> reset gate never used
    const float* Wh  = (const float*)d_in[6];
    const float* bh  = (const float*)d_in[7];
    const float* lzW = (const float*)d_in[8];
    const float* lzb = (const float*)d_in[9];
    // d_in[10], d_in[11] (lr_W, lr_b) dead too
    const float* lhW = (const float*)d_in[12];
    const float* lhb = (const float*)d_in[13];
    const float* att = (const float*)d_in[14];
    const float* l1W = (const float*)d_in[15];
    const float* l1b = (const float*)d_in[16];
    const float* l2W = (const float*)d_in[17];
    const float* l2b = (const float*)d_in[18];

    float* out = (float*)d_out;
    const int B = in_sizes[0] / (NN * FD * PP);   // 1024

    fused_k<<<B, 256, 0, stream>>>(x, ei, Wz, bz, Wh, bh, lzW, lzb, lhW, lhb,
                                   att, l1W, l1b, l2W, l2b, out);
}

// Round 5
// 128.255 us; speedup vs baseline: 1.4157x; 1.2042x over previous
//
#include <hip/hip_runtime.h>

#define NN   21   // nodes
#define NE   60   // edges (before self-loops)
#define FD   3    // input features
#define HD   32   // hidden
#define PP   64   // periods
#define OUTC 6    // output channels
#define LOG2E 1.44269504088896f

// ws float offsets (written by setup_k, read by main_k)
#define WS_A    0      // 504 = 21 rows x 24 padded cols, dense normalized adjacency
#define WS_WZ   504    // 96  W'_z = (W_z @ lzW_top) * log2e       [f*32+o]
#define WS_WH   600    // 96  W'_h = (W_h @ lhW_top) * 2*log2e
#define WS_BZ   696    // 32  b'_z scaled by log2e
#define WS_BH   728    // 32  b'_h scaled by 2*log2e
#define WS_PROB 760    // 64  softmax(att)
#define WS_M    824    // 384 M[c][p] = Sc[c]*l1b[p] + l2b[c]

#if defined(__has_builtin)
#  if __has_builtin(__builtin_amdgcn_exp2f)
#    define EXP2(x) __builtin_amdgcn_exp2f(x)
#  else
#    define EXP2(x) exp2f(x)
#  endif
#else
#  define EXP2(x) exp2f(x)
#endif
#define RCP(x) __builtin_amdgcn_rcpf(x)

// ---------------------------------------------------------------------------
// setup_k: one block, fully parallel (no runtime-indexed register arrays).
// Builds padded dense A, scaled fused gate weights, probs, and M.
// ---------------------------------------------------------------------------
__global__ void setup_k(const int* __restrict__ edge,
                        const float* __restrict__ Wz, const float* __restrict__ bz,
                        const float* __restrict__ Wh, const float* __restrict__ bh,
                        const float* __restrict__ lzW, const float* __restrict__ lzb,
                        const float* __restrict__ lhW, const float* __restrict__ lhb,
                        const float* __restrict__ att, const float* __restrict__ l1b,
                        const float* __restrict__ l2W, const float* __restrict__ l2b,
                        float* __restrict__ ws) {
    __shared__ float sA[NN * NN];
    __shared__ float degS[NN];
    __shared__ float ScS[OUTC];
    const int t = threadIdx.x;

    for (int i = t; i < NN * NN; i += 256) sA[i] = 0.f;
    if (t < NN) degS[t] = 1.f;                      // self-loop
    __syncthreads();

    if (t < NE) atomicAdd(&degS[edge[NE + t]], 1.f);
    __syncthreads();

    if (t < NN) degS[t] = rsqrtf(degS[t]);
    __syncthreads();

    // adjacency atomics + diagonal + weight fusion + softmax + Sc, all parallel
    if (t < NE) {
        int s = edge[t], d = edge[NE + t];
        atomicAdd(&sA[d * NN + s], degS[s] * degS[d]);
    }
    if (t >= 64 && t < 64 + NN) {
        int n = t - 64;
        atomicAdd(&sA[n * NN + n], degS[n] * degS[n]);
    }
    if (t >= 96 && t < 192) {                       // W' = W @ lW_top, scaled
        int i = t - 96, f = i >> 5, o = i & 31;
        float az = 0.f, ah = 0.f;
        for (int k = 0; k < HD; ++k) {
            az = fmaf(Wz[f * HD + k], lzW[k * HD + o], az);
            ah = fmaf(Wh[f * HD + k], lhW[k * HD + o], ah);
        }
        ws[WS_WZ + i] = az * LOG2E;
        ws[WS_WH + i] = ah * (2.f * LOG2E);
    }
    if (t >= 192 && t < 224) {                      // b' scaled
        int o = t - 192;
        float az = lzb[o], ah = lhb[o];
        for (int k = 0; k < HD; ++k) {
            az = fmaf(bz[k], lzW[k * HD + o], az);
            ah = fmaf(bh[k], lhW[k * HD + o], ah);
        }
        ws[WS_BZ + o] = az * LOG2E;
        ws[WS_BH + o] = ah * (2.f * LOG2E);
    }
    if (t < 64) {                                   // softmax(att), wave 0
        float a = att[t], m = a;
        #pragma unroll
        for (int msk = 32; msk >= 1; msk >>= 1) m = fmaxf(m, __shfl_xor(m, msk, 64));
        float e = __expf(a - m);
        float ssum = e;
        #pragma unroll
        for (int msk = 32; msk >= 1; msk >>= 1) ssum += __shfl_xor(ssum, msk, 64);
        ws[WS_PROB + t] = e / ssum;
    }
    if (t >= 224 && t < 224 + OUTC) {               // Sc[c] = sum_n l2W[n][c]
        int c = t - 224;
        float s = 0.f;
        for (int n = 0; n < NN; ++n) s += l2W[n * OUTC + c];
        ScS[c] = s;
    }
    __syncthreads();

    // write padded A (zeros in cols 21..23) and M
    for (int i = t; i < NN * 24; i += 256) {
        int r = i / 24, cm = i % 24;
        ws[WS_A + i] = (cm < NN) ? sA[r * NN + cm] : 0.f;
    }
    for (int i = t; i < OUTC * PP; i += 256) {
        int c = i >> 6, p = i & 63;
        ws[WS_M + i] = fmaf(ScS[c], l1b[p], l2b[c]);
    }
}

// ---------------------------------------------------------------------------
// main_k: one block (512 threads = 8 waves) per batch element; 4 blocks/CU
// -> 32 waves/CU (100% occupancy). 4 barriers total.
// ---------------------------------------------------------------------------
// per-eval gate math: az,ah prescaled by log2e so exp2 is direct.
#define EVAL(Y0,Y1,Y2,PR) do {                                                  \
    float az0_ = fmaf((Y2), wz02, fmaf((Y1), wz01, fmaf((Y0), wz00, bz0)));     \
    float ah0_ = fmaf((Y2), wh02, fmaf((Y1), wh01, fmaf((Y0), wh00, bh0)));     \
    float w0_  = RCP(1.f + EXP2(az0_));                                         \
    float h0_  = fmaf(-2.f, RCP(1.f + EXP2(ah0_)), 1.f);                        \
    acc0 = fmaf((PR) * w0_, h0_, acc0);                                         \
    float az1_ = fmaf((Y2), wz12, fmaf((Y1), wz11, fmaf((Y0), wz10, bz1)));     \
    float ah1_ = fmaf((Y2), wh12, fmaf((Y1), wh11, fmaf((Y0), wh10, bh1)));     \
    float w1_  = RCP(1.f + EXP2(az1_));                                         \
    float h1_  = fmaf(-2.f, RCP(1.f + EXP2(ah1_)), 1.f);                        \
    acc1 = fmaf((PR) * w1_, h1_, acc1);                                         \
} while (0)

__global__ __launch_bounds__(512, 8) void main_k(
    const float* __restrict__ x,  const float* __restrict__ ws,
    const float* __restrict__ l1W, const float* __restrict__ l2W,
    float* __restrict__ out)
{
    __shared__ __align__(16) float Xs[NN * FD * PP];   // 16128 B
    __shared__ __align__(16) float Ys[NN * FD * PP];   // 16128 B
    __shared__ __align__(16) float AsP[NN * 24];       // 2016 B padded A
    __shared__ __align__(16) float Cs[320];            // W'z|W'h|b'z|b'h|probs
    __shared__ float Hs[NN * HD];                      // 2688 B
    __shared__ float G[OUTC * HD];                     // 768 B

    const int t = threadIdx.x;
    const int b = blockIdx.x;
    const float* xb = x + (size_t)b * (NN * FD * PP);

    // ---- stage 0: coalesced loads into LDS
    {
        const float4* xb4 = (const float4*)xb;
        float4* Xs4 = (float4*)Xs;
        Xs4[t] = xb4[t];
        if (t < 496) Xs4[512 + t] = xb4[512 + t];           // 1008 float4 total
        if (t < 126) ((float4*)AsP)[t] = ((const float4*)ws)[t];
        if (t >= 128 && t < 208)
            ((float4*)Cs)[t - 128] = ((const float4*)(ws + WS_WZ))[t - 128];
    }
    __syncthreads();

    // ---- stage 1: Y = A @ X, skipping zero A entries (A is ~82% zeros)
    {
        const float4* Xs4 = (const float4*)Xs;
        float4* Ys4 = (float4*)Ys;
        for (int i = t; i < NN * FD * PP / 4; i += 512) {
            const int p4 = i & 15;
            const int fn = i >> 4;          // n*3 + f
            const int n  = fn / 3;
            const int f  = fn - n * 3;
            const float4* An4 = (const float4*)(AsP + n * 24);
            float4 acc = {0.f, 0.f, 0.f, 0.f};
            #pragma unroll
            for (int mq = 0; mq < 6; ++mq) {
                const float4 a = An4[mq];
                // padding cols are exactly 0 -> guarded X reads never go OOB
                if (a.x != 0.f) { const float4 xv = Xs4[((mq*4+0)*3+f)*16 + p4];
                    acc.x=fmaf(a.x,xv.x,acc.x); acc.y=fmaf(a.x,xv.y,acc.y);
                    acc.z=fmaf(a.x,xv.z,acc.z); acc.w=fmaf(a.x,xv.w,acc.w); }
                if (a.y != 0.f) { const float4 xv = Xs4[((mq*4+1)*3+f)*16 + p4];
                    acc.x=fmaf(a.y,xv.x,acc.x); acc.y=fmaf(a.y,xv.y,acc.y);
                    acc.z=fmaf(a.y,xv.z,acc.z); acc.w=fmaf(a.y,xv.w,acc.w); }
                if (a.z != 0.f) { const float4 xv = Xs4[((mq*4+2)*3+f)*16 + p4];
                    acc.x=fmaf(a.z,xv.x,acc.x); acc.y=fmaf(a.z,xv.y,acc.y);
                    acc.z=fmaf(a.z,xv.z,acc.z); acc.w=fmaf(a.z,xv.w,acc.w); }
                if (a.w != 0.f) { const float4 xv = Xs4[((mq*4+3)*3+f)*16 + p4];
                    acc.x=fmaf(a.w,xv.x,acc.x); acc.y=fmaf(a.w,xv.y,acc.y);
                    acc.z=fmaf(a.w,xv.z,acc.z); acc.w=fmaf(a.w,xv.w,acc.w); }
            }
            Ys4[fn * 16 + p4] = acc;
        }
    }
    __syncthreads();

    // ---- stage 2: Hs[n][o] = relu( sum_p probs[p]*(1-Z)*tanh )
    // lane decode: ps = p-slice (8 p's), og = o-pair, c4 = n offset.
    // 8 lanes (ps=0..7) cooperate on one (n, o-pair); p-sum via 3x shfl_xor.
    // Y reads are wave-broadcast (8 lanes share each address).
    {
        const int ps = t & 7;
        const int og = (t >> 3) & 15;
        const int c4 = t >> 7;                       // 0..3, uniform per wave
        const int o0 = og * 2, o1 = o0 + 1;
        const float wz00 = Cs[o0],      wz01 = Cs[32+o0],  wz02 = Cs[64+o0];
        const float wz10 = Cs[o1],      wz11 = Cs[32+o1],  wz12 = Cs[64+o1];
        const float wh00 = Cs[96+o0],   wh01 = Cs[128+o0], wh02 = Cs[160+o0];
        const float wh10 = Cs[96+o1],   wh11 = Cs[128+o1], wh12 = Cs[160+o1];
        const float bz0  = Cs[192+o0],  bz1  = Cs[192+o1];
        const float bh0  = Cs[224+o0],  bh1  = Cs[224+o1];
        const float4 pr0 = *(const float4*)&Cs[256 + ps*8];
        const float4 pr1 = *(const float4*)&Cs[256 + ps*8 + 4];
        #pragma unroll
        for (int s = 0; s < 6; ++s) {
            const int n = c4 + 4 * s;
            if (n < NN) {                            // uniform per wave
                const float4* Yn4 = (const float4*)(Ys + n * FD * PP) + ps * 2;
                float acc0 = 0.f, acc1 = 0.f;
                float4 y0 = Yn4[0], y1 = Yn4[16], y2 = Yn4[32];
                EVAL(y0.x,y1.x,y2.x, pr0.x); EVAL(y0.y,y1.y,y2.y, pr0.y);
                EVAL(y0.z,y1.z,y2.z, pr0.z); EVAL(y0.w,y1.w,y2.w, pr0.w);
                y0 = Yn4[1]; y1 = Yn4[17]; y2 = Yn4[33];
                EVAL(y0.x,y1.x,y2.x, pr1.x); EVAL(y0.y,y1.y,y2.y, pr1.y);
                EVAL(y0.z,y1.z,y2.z, pr1.z); EVAL(y0.w,y1.w,y2.w, pr1.w);
                acc0 += __shfl_xor(acc0, 1); acc0 += __shfl_xor(acc0, 2); acc0 += __shfl_xor(acc0, 4);
                acc1 += __shfl_xor(acc1, 1); acc1 += __shfl_xor(acc1, 2); acc1 += __shfl_xor(acc1, 4);
                if (ps == 0) {
                    Hs[n * HD + o0] = fmaxf(acc0, 0.f);
                    Hs[n * HD + o1] = fmaxf(acc1, 0.f);
                }
            }
        }
    }
    __syncthreads();

    // ---- stage 3': G[c,o] = sum_n l2W[n][c] * Hs[n][o]
    if (t < OUTC * HD) {
        const int c = t >> 5, o = t & 31;
        float g = 0.f;
        #pragma unroll
        for (int n = 0; n < NN; ++n)
            g = fmaf(l2W[n * OUTC + c], Hs[n * HD + o], g);
        G[t] = g;
    }
    __syncthreads();

    // ---- stage 4': out[b,c,p] = sum_o G[c,o]*l1W[o,p] + M[c,p]
    if (t < OUTC * PP) {
        const int c = t >> 6, p = t & 63;
        const float* Gc = G + c * HD;
        float a0 = 0.f, a1 = 0.f, a2 = 0.f, a3 = 0.f;
        #pragma unroll
        for (int o = 0; o < HD; o += 4) {
            a0 = fmaf(Gc[o+0], l1W[(o+0) * PP + p], a0);
            a1 = fmaf(Gc[o+1], l1W[(o+1) * PP + p], a1);
            a2 = fmaf(Gc[o+2], l1W[(o+2) * PP + p], a2);
            a3 = fmaf(Gc[o+3], l1W[(o+3) * PP + p], a3);
        }
        out[(size_t)b * (OUTC * PP) + t] = ws[WS_M + t] + (a0 + a1) + (a2 + a3);
    }
}

extern "C" void kernel_launch(void* const* d_in, const int* in_sizes, int n_in,
                              void* d_out, int out_size, void* d_ws, size_t ws_size,
                              hipStream_t stream) {
    const float* x   = (const float*)d_in[0];
    const int*   ei  = (const int*)  d_in[1];
    const float* Wz  = (const float*)d_in[2];
    const float* bz  = (const float*)d_in[3];
    // d_in[4], d_in[5] (W_r, b_r) dead: H=0 -> reset gate never used
    const float* Wh  = (const float*)d_in[6];
    const float* bh  = (const float*)d_in[7];
    const float* lzW = (const float*)d_in[8];
    const float* lzb = (const float*)d_in[9];
    // d_in[10], d_in[11] (lr_W, lr_b) dead too
    const float* lhW = (const float*)d_in[12];
    const float* lhb = (const float*)d_in[13];
    const float* att = (const float*)d_in[14];
    const float* l1W = (const float*)d_in[15];
    const float* l1b = (const float*)d_in[16];
    const float* l2W = (const float*)d_in[17];
    const float* l2b = (const float*)d_in[18];

    float* out = (float*)d_out;
    float* ws  = (float*)d_ws;

    const int B = in_sizes[0] / (NN * FD * PP);   // 1024

    setup_k<<<1, 256, 0, stream>>>(ei, Wz, bz, Wh, bh, lzW, lzb, lhW, lhb,
                                   att, l1b, l2W, l2b, ws);
    main_k<<<B, 512, 0, stream>>>(x, ws, l1W, l2W, out);
}

// Round 6
// 127.969 us; speedup vs baseline: 1.4188x; 1.0022x over previous
//
#include <hip/hip_runtime.h>

#define NN   21   // nodes
#define NE   60   // edges (before self-loops)
#define FD   3    // input features
#define HD   32   // hidden
#define PP   64   // periods
#define OUTC 6    // output channels
#define LOG2E 1.44269504088896f

#if defined(__has_builtin)
#  if __has_builtin(__builtin_amdgcn_exp2f)
#    define EXP2(x) __builtin_amdgcn_exp2f(x)
#  else
#    define EXP2(x) exp2f(x)
#  endif
#else
#  define EXP2(x) exp2f(x)
#endif
#define RCP(x) __builtin_amdgcn_rcpf(x)

// ---------------------------------------------------------------------------
// Fully fused: ONE kernel, one block (512 thr = 8 waves) per batch element,
// no d_ws (round-4 evidence: no-ws runs had the lowest harness overhead).
// Each block redoes the tiny setup (~1 us, parallel everywhere):
//   deg scatter -> A[d][s] += dinv_s*dinv_d (rsqrt inline) ;  W' = W@lW_top
//   (log2e-prescaled) ; probs = softmax(att) ; Sc[c] = sum_n l2W[n][c].
// Algebra (H=0): Hn = (1-Z)*tanh(..), pooled over p; l1/l2 have no
// nonlinearity between them:
//   out[c,p] = sum_o G[c,o]*l1W[o,p] + Sc[c]*l1b[p] + l2b[c],
//   G[c,o]   = sum_n l2W[n,c]*relu(Hpool[n,o]).
// Gate eval (3 trans, 11 VALU):  pr*(1-Z)*tanh = fmaf(pr,e2,-pr) * rcp((1+ea)(1+e2))
//   with ea = 2^(az*log2e), e2 = 2^(ah*2log2e)  (scales folded into W',b').
// ---------------------------------------------------------------------------
#define EVAL(Y0,Y1,Y2,PR) do {                                                  \
    float az0_ = fmaf((Y2), wz02, fmaf((Y1), wz01, fmaf((Y0), wz00, bz0)));     \
    float ah0_ = fmaf((Y2), wh02, fmaf((Y1), wh01, fmaf((Y0), wh00, bh0)));     \
    float ea0_ = EXP2(az0_), e20_ = EXP2(ah0_);                                 \
    float r0_  = RCP((1.f + ea0_) * (1.f + e20_));                              \
    acc0 = fmaf(fmaf((PR), e20_, -(PR)), r0_, acc0);                            \
    float az1_ = fmaf((Y2), wz12, fmaf((Y1), wz11, fmaf((Y0), wz10, bz1)));     \
    float ah1_ = fmaf((Y2), wh12, fmaf((Y1), wh11, fmaf((Y0), wh10, bh1)));     \
    float ea1_ = EXP2(az1_), e21_ = EXP2(ah1_);                                 \
    float r1_  = RCP((1.f + ea1_) * (1.f + e21_));                              \
    acc1 = fmaf(fmaf((PR), e21_, -(PR)), r1_, acc1);                            \
} while (0)

__global__ __launch_bounds__(512, 8) void fused_k(
    const float* __restrict__ x,   const int* __restrict__ edge,
    const float* __restrict__ Wz,  const float* __restrict__ bz,
    const float* __restrict__ Wh,  const float* __restrict__ bh,
    const float* __restrict__ lzW, const float* __restrict__ lzb,
    const float* __restrict__ lhW, const float* __restrict__ lhb,
    const float* __restrict__ att,
    const float* __restrict__ l1W, const float* __restrict__ l1b,
    const float* __restrict__ l2W, const float* __restrict__ l2b,
    float* __restrict__ out)
{
    // LDS: 16128 + 16128 + 2016 + 1408 + 2688 + 768 = 39136 B -> 4 blocks/CU
    __shared__ __align__(16) float Xs[NN * FD * PP]; // x[b]; post-stage1: l1W overlay
    __shared__ __align__(16) float Ys[NN * FD * PP]; // Y = A@X; post-stage2: M overlay
    __shared__ __align__(16) float AsP[NN * 24];     // padded adjacency
    __shared__ __align__(16) float Cs[352];          // W'z|W'h|b'z|b'h|probs|deg|Sc
    __shared__ float Hs[NN * HD];
    __shared__ float G[OUTC * HD];

    const int t = threadIdx.x;
    const int b = blockIdx.x;
    const float* xb = x + (size_t)b * (NN * FD * PP);

    // ---- Phase A: x -> Xs (float4, coalesced); zero A; deg = 1 (self-loop)
    {
        const float4* xb4 = (const float4*)xb;
        float4* Xs4 = (float4*)Xs;
        Xs4[t] = xb4[t];
        if (t < 496) Xs4[512 + t] = xb4[512 + t];     // 1008 float4 total
        for (int i = t; i < NN * 24; i += 512) AsP[i] = 0.f;
        if (t < NN) Cs[320 + t] = 1.f;
    }
    __syncthreads();

    // ---- Phase B: deg scatter | W' fusion | biases | softmax | Sc (disjoint)
    if (t < NE) {
        atomicAdd(&Cs[320 + edge[NE + t]], 1.f);
    } else if (t >= 64 && t < 160) {                  // W' = W @ lW_top, scaled
        int i = t - 64, f = i >> 5, o = i & 31;
        float az = 0.f, ah = 0.f;
        #pragma unroll
        for (int k = 0; k < HD; ++k) {
            az = fmaf(Wz[f * HD + k], lzW[k * HD + o], az);
            ah = fmaf(Wh[f * HD + k], lhW[k * HD + o], ah);
        }
        Cs[i] = az * LOG2E;                           // W'z
        Cs[96 + i] = ah * (2.f * LOG2E);              // W'h
    } else if (t >= 160 && t < 192) {                 // fused biases
        int o = t - 160;
        float az = lzb[o], ah = lhb[o];
        #pragma unroll
        for (int k = 0; k < HD; ++k) {
            az = fmaf(bz[k], lzW[k * HD + o], az);
            ah = fmaf(bh[k], lhW[k * HD + o], ah);
        }
        Cs[192 + o] = az * LOG2E;
        Cs[224 + o] = ah * (2.f * LOG2E);
    } else if (t >= 192 && t < 256) {                 // softmax(att), wave 3
        int l = t - 192;
        float a = att[l], m = a;
        #pragma unroll
        for (int msk = 32; msk >= 1; msk >>= 1) m = fmaxf(m, __shfl_xor(m, msk, 64));
        float e = __expf(a - m);
        float ssum = e;
        #pragma unroll
        for (int msk = 32; msk >= 1; msk >>= 1) ssum += __shfl_xor(ssum, msk, 64);
        Cs[256 + l] = e / ssum;
    } else if (t >= 256 && t < 256 + OUTC) {          // Sc[c] = sum_n l2W[n][c]
        int c = t - 256;
        float s = 0.f;
        for (int n = 0; n < NN; ++n) s += l2W[n * OUTC + c];
        Cs[344 + c] = s;
    }
    __syncthreads();

    // ---- Phase C: adjacency atomics, rsqrt inline (no extra barrier)
    if (t < NE) {
        int s = edge[t], d = edge[NE + t];
        atomicAdd(&AsP[d * 24 + s], rsqrtf(Cs[320 + s]) * rsqrtf(Cs[320 + d]));
    } else if (t >= 64 && t < 64 + NN) {
        int n = t - 64;
        atomicAdd(&AsP[n * 24 + n], RCP(Cs[320 + n]));  // dinv^2 = 1/deg
    }
    __syncthreads();

    // ---- Stage 1: Y = A @ X, skipping zero A entries (A ~82% zeros)
    {
        const float4* Xs4 = (const float4*)Xs;
        float4* Ys4 = (float4*)Ys;
        for (int i = t; i < NN * FD * PP / 4; i += 512) {
            const int p4 = i & 15;
            const int fn = i >> 4;            // n*3 + f
            const int n  = fn / 3;
            const int f  = fn - n * 3;
            const float4* An4 = (const float4*)(AsP + n * 24);
            float4 acc = {0.f, 0.f, 0.f, 0.f};
            #pragma unroll
            for (int mq = 0; mq < 6; ++mq) {
                const float4 a = An4[mq];
                if (a.x != 0.f) { const float4 xv = Xs4[((mq*4+0)*3+f)*16 + p4];
                    acc.x=fmaf(a.x,xv.x,acc.x); acc.y=fmaf(a.x,xv.y,acc.y);
                    acc.z=fmaf(a.x,xv.z,acc.z); acc.w=fmaf(a.x,xv.w,acc.w); }
                if (a.y != 0.f) { const float4 xv = Xs4[((mq*4+1)*3+f)*16 + p4];
                    acc.x=fmaf(a.y,xv.x,acc.x); acc.y=fmaf(a.y,xv.y,acc.y);
                    acc.z=fmaf(a.y,xv.z,acc.z); acc.w=fmaf(a.y,xv.w,acc.w); }
                if (a.z != 0.f) { const float4 xv = Xs4[((mq*4+2)*3+f)*16 + p4];
                    acc.x=fmaf(a.z,xv.x,acc.x); acc.y=fmaf(a.z,xv.y,acc.y);
                    acc.z=fmaf(a.z,xv.z,acc.z); acc.w=fmaf(a.z,xv.w,acc.w); }
                if (a.w != 0.f) { const float4 xv = Xs4[((mq*4+3)*3+f)*16 + p4];
                    acc.x=fmaf(a.w,xv.x,acc.x); acc.y=fmaf(a.w,xv.y,acc.y);
                    acc.z=fmaf(a.w,xv.z,acc.z); acc.w=fmaf(a.w,xv.w,acc.w); }
            }
            Ys4[fn * 16 + p4] = acc;
        }
    }
    __syncthreads();

    // ---- l1W -> dead Xs region (global load + LDS write; Xs reads done)
    ((float4*)Xs)[t] = ((const float4*)l1W)[t];       // 512 x 16B = 2048 floats

    // ---- Stage 2: Hpool[n][o] = sum_p probs[p]*(1-Z)*tanh ; relu fused
    // lane: ps = t&7 (8 p's), o-pair = (t>>3)&15, n-offset = t>>7; p-sum via shfl
    {
        const int ps = t & 7;
        const int og = (t >> 3) & 15;
        const int c4 = t >> 7;                        // 0..3, wave-uniform
        const int o0 = og * 2, o1 = o0 + 1;
        const float wz00 = Cs[o0],     wz01 = Cs[32+o0],  wz02 = Cs[64+o0];
        const float wz10 = Cs[o1],     wz11 = Cs[32+o1],  wz12 = Cs[64+o1];
        const float wh00 = Cs[96+o0],  wh01 = Cs[128+o0], wh02 = Cs[160+o0];
        const float wh10 = Cs[96+o1],  wh11 = Cs[128+o1], wh12 = Cs[160+o1];
        const float bz0  = Cs[192+o0], bz1  = Cs[192+o1];
        const float bh0  = Cs[224+o0], bh1  = Cs[224+o1];
        const float4 pr0 = *(const float4*)&Cs[256 + ps*8];
        const float4 pr1 = *(const float4*)&Cs[256 + ps*8 + 4];
        #pragma unroll
        for (int s = 0; s < 6; ++s) {
            const int n = c4 + 4 * s;
            if (n < NN) {                             // wave-uniform guard
                const float4* Yn4 = (const float4*)(Ys + n * FD * PP) + ps * 2;
                float acc0 = 0.f, acc1 = 0.f;
                float4 y0 = Yn4[0], y1 = Yn4[16], y2 = Yn4[32];
                EVAL(y0.x,y1.x,y2.x, pr0.x); EVAL(y0.y,y1.y,y2.y, pr0.y);
                EVAL(y0.z,y1.z,y2.z, pr0.z); EVAL(y0.w,y1.w,y2.w, pr0.w);
                y0 = Yn4[1]; y1 = Yn4[17]; y2 = Yn4[33];
                EVAL(y0.x,y1.x,y2.x, pr1.x); EVAL(y0.y,y1.y,y2.y, pr1.y);
                EVAL(y0.z,y1.z,y2.z, pr1.z); EVAL(y0.w,y1.w,y2.w, pr1.w);
                acc0 += __shfl_xor(acc0, 1); acc0 += __shfl_xor(acc0, 2); acc0 += __shfl_xor(acc0, 4);
                acc1 += __shfl_xor(acc1, 1); acc1 += __shfl_xor(acc1, 2); acc1 += __shfl_xor(acc1, 4);
                if (ps == 0) {
                    Hs[n * HD + o0] = fmaxf(acc0, 0.f);
                    Hs[n * HD + o1] = fmaxf(acc1, 0.f);
                }
            }
        }
    }
    __syncthreads();

    // ---- Stage 3': G[c,o] (t<192)  ||  M[c,p] -> dead Ys[0..383] (t>=192)
    if (t < OUTC * HD) {
        const int c = t >> 5, o = t & 31;
        float g = 0.f;
        #pragma unroll
        for (int n = 0; n < NN; ++n)
            g = fmaf(l2W[n * OUTC + c], Hs[n * HD + o], g);
        G[t] = g;
    } else {
        for (int i = t - 192; i < OUTC * PP; i += 320) {
            const int c = i >> 6, p = i & 63;
            Ys[i] = fmaf(Cs[344 + c], l1b[p], l2b[c]);
        }
    }
    __syncthreads();

    // ---- Stage 4': out[b,c,p] = sum_o G[c,o]*l1W[o,p] + M[c,p]
    if (t < OUTC * PP) {
        const int c = t >> 6, p = t & 63;
        const float* Gc = G + c * HD;
        const float* l1Ws = Xs;                       // overlaid [32][64]
        float a0 = 0.f, a1 = 0.f, a2 = 0.f, a3 = 0.f;
        #pragma unroll
        for (int o = 0; o < HD; o += 4) {
            a0 = fmaf(Gc[o+0], l1Ws[(o+0) * PP + p], a0);
            a1 = fmaf(Gc[o+1], l1Ws[(o+1) * PP + p], a1);
            a2 = fmaf(Gc[o+2], l1Ws[(o+2) * PP + p], a2);
            a3 = fmaf(Gc[o+3], l1Ws[(o+3) * PP + p], a3);
        }
        out[(size_t)b * (OUTC * PP) + t] = Ys[t] + (a0 + a1) + (a2 + a3);
    }
}

extern "C" void kernel_launch(void* const* d_in, const int* in_sizes, int n_in,
                              void* d_out, int out_size, void* d_ws, size_t ws_size,
                              hipStream_t stream) {
    const float* x   = (const float*)d_in[0];
    const int*   ei  = (const int*)  d_in[1];
    const float* Wz  = (const float*)d_in[2];
    const float* bz  = (const float*)d_in[3];
    // d_in[4], d_in[5] (W_r, b_r) dead: H=0 -> reset gate never used
    const float* Wh  = (const float*)d_in[6];
    const float* bh  = (const float*)d_in[7];
    const float* lzW = (const float*)d_in[8];
    const float* lzb = (const float*)d_in[9];
    // d_in[10], d_in[11] (lr_W, lr_b) dead too
    const float* lhW = (const float*)d_in[12];
    const float* lhb = (const float*)d_in[13];
    const float* att = (const float*)d_in[14];
    const float* l1W = (const float*)d_in[15];
    const float* l1b = (const float*)d_in[16];
    const float* l2W = (const float*)d_in[17];
    const float* l2b = (const float*)d_in[18];

    float* out = (float*)d_out;
    const int B = in_sizes[0] / (NN * FD * PP);   // 1024

    fused_k<<<B, 512, 0, stream>>>(x, ei, Wz, bz, Wh, bh, lzW, lzb, lhW, lhb,
                                   att, l1W, l1b, l2W, l2b, out);
}